// Round 1
// baseline (120.683 us; speedup 1.0000x reference)
//
#include <hip/hip_runtime.h>

// ROI bilinear pooling: img (1,200,200,512) fp32, rois (1,300,4) int32 [x,y,w,h]
// out (1,300,7,7,512) fp32.
// One block per (roi, py, px); 128 threads x float4 = 512 channels.

#define IMG_W 200
#define NCH   512
#define NPOS  49   // 7*7

__global__ __launch_bounds__(128) void roi_bilinear_kernel(
    const float* __restrict__ img,
    const int*   __restrict__ rois,
    float*       __restrict__ out)
{
    int bid = blockIdx.x;            // r*49 + py*7 + px
    int r   = bid / NPOS;
    int rem = bid - r * NPOS;
    int py  = rem / 7;
    int px  = rem - py * 7;

    int x0 = rois[4 * r + 0];
    int y0 = rois[4 * r + 1];
    int w  = rois[4 * r + 2];
    int h  = rois[4 * r + 3];

    // Strict IEEE fp32, op-for-op identical to the numpy/jax reference:
    // scale = h/7.0f; ys = y0 + py*scale  (NO fma contraction allowed)
    float sy = __fdiv_rn((float)h, 7.0f);
    float sx = __fdiv_rn((float)w, 7.0f);
    float ys = __fadd_rn((float)y0, __fmul_rn((float)py, sy));
    float xs = __fadd_rn((float)x0, __fmul_rn((float)px, sx));

    int ty = (int)floorf(ys);
    int tx = (int)floorf(xs);
    float fy = __fsub_rn(ys, (float)ty);
    float fx = __fsub_rn(xs, (float)tx);

    int by = min(ty + 1, y0 + h - 1);
    int bx = min(tx + 1, x0 + w - 1);

    const float4* p00 = (const float4*)(img + (size_t)(ty * IMG_W + tx) * NCH);
    const float4* p01 = (const float4*)(img + (size_t)(ty * IMG_W + bx) * NCH);
    const float4* p10 = (const float4*)(img + (size_t)(by * IMG_W + tx) * NCH);
    const float4* p11 = (const float4*)(img + (size_t)(by * IMG_W + bx) * NCH);
    float4*       po  = (float4*)(out + (size_t)bid * NCH);

    int t = threadIdx.x;   // 0..127, 4 channels each
    float4 v00 = p00[t];
    float4 v01 = p01[t];
    float4 v10 = p10[t];
    float4 v11 = p11[t];

    float gx = 1.0f - fx;
    float gy = 1.0f - fy;

    float4 o;
    o.x = gy * (gx * v00.x + fx * v01.x) + fy * (gx * v10.x + fx * v11.x);
    o.y = gy * (gx * v00.y + fx * v01.y) + fy * (gx * v10.y + fx * v11.y);
    o.z = gy * (gx * v00.z + fx * v01.z) + fy * (gx * v10.z + fx * v11.z);
    o.w = gy * (gx * v00.w + fx * v01.w) + fy * (gx * v10.w + fx * v11.w);
    po[t] = o;
}

extern "C" void kernel_launch(void* const* d_in, const int* in_sizes, int n_in,
                              void* d_out, int out_size, void* d_ws, size_t ws_size,
                              hipStream_t stream)
{
    const float* img  = (const float*)d_in[0];   // 1*200*200*512 fp32
    const int*   rois = (const int*)d_in[1];     // 1*300*4 int32
    float*       out  = (float*)d_out;           // 1*300*7*7*512 fp32

    const int nroi = in_sizes[1] / 4;            // 300
    dim3 grid(nroi * NPOS);                      // 14700 blocks
    dim3 block(128);
    roi_bilinear_kernel<<<grid, block, 0, stream>>>(img, rois, out);
}